// Round 14
// baseline (173.687 us; speedup 1.0000x reference)
//
#include <hip/hip_runtime.h>
#include <math.h>

// ---------------------------------------------------------------------------
// spline_net r14: tiled-LDS gemm (coalesced x staging), packed 4B edge
// records after sort, unrolled gathers.
//   r13 counters: phase1 69us, VALU 19%, occ 31%, FETCH 38MB (L3-resident
//   inputs) -> gemm latency-bound on strided x loads. Rebuild gemm: stage
//   32 nodes of x in LDS coalesced, 8 thr/node x 6 cols, acc[6]. csr_build
//   now emits {src:17,w:15fixed} u32 records in place (same per-bucket byte
//   region -> no cross-block race); gathers read 4B/record with unroll 4.
// N=100000, F_IN=128, HID=16, C=10, E=1600000
// ---------------------------------------------------------------------------

#define SHIFT    7            // 128 nodes per bucket
#define BNODES   128
#define NBUK_MAX 800          // supports N <= 102400
#define CAP      2432         // bucket capacity; mean 2046, sigma ~45 -> +8.5σ
#define CHUNK    4096         // edges per bin block
#define GTN      32           // nodes per gemm tile
#define XPITCH   132          // x_lds row pitch (floats): 16B-aligned, ~2-way

__device__ __forceinline__ unsigned short f2bf(float f) {
    unsigned int u = __float_as_uint(f);
    u += 0x7FFF + ((u >> 16) & 1);        // round to nearest even
    return (unsigned short)(u >> 16);
}

// ---- fused phase 1: tiled gemm + bin -----------------------------------

__device__ __forceinline__ void gemm_part(
    float* __restrict__ smem, int gb, int tid,
    const float* __restrict__ x, const float* __restrict__ W1,
    const float* __restrict__ root1, unsigned int* __restrict__ h01i,
    float* __restrict__ xr, int N)
{
    float* xls = smem;                 // [GTN][XPITCH]
    float* Ws  = smem + GTN * XPITCH;  // [128][48] natural: j<16 W1[0], <32 W1[1], else root1
    for (int idx = tid; idx < 128 * 48; idx += 256) {
        int k = idx / 48, j = idx % 48;
        float v = (j < 16) ? W1[k * 16 + j]
                : (j < 32) ? W1[2048 + k * 16 + (j - 16)]
                           : root1[k * 16 + (j - 32)];
        Ws[idx] = v;
    }
    int node0 = gb * GTN;
    for (int f = tid; f < GTN * 32; f += 256) {     // 1024 float4s, coalesced
        int n = f >> 5, k4 = f & 31;
        float4 v = make_float4(0.f, 0.f, 0.f, 0.f);
        if (node0 + n < N)
            v = ((const float4*)(x + (size_t)(node0 + n) * 128))[k4];
        *(float4*)(xls + n * XPITCH + k4 * 4) = v;
    }
    __syncthreads();

    int n = tid >> 3;          // 0..31
    int q = tid & 7;           // col group: cols 6q..6q+5
    float acc[6] = {0.f, 0.f, 0.f, 0.f, 0.f, 0.f};
    const float* wq = Ws + q * 6;
#pragma unroll 4
    for (int k4 = 0; k4 < 32; ++k4) {
        float4 xv = *(const float4*)(xls + n * XPITCH + k4 * 4);
        float xs[4] = {xv.x, xv.y, xv.z, xv.w};
#pragma unroll
        for (int kk = 0; kk < 4; ++kk) {
            const float* wr = wq + (k4 * 4 + kk) * 48;
            float xk = xs[kk];
            acc[0] += xk * wr[0]; acc[1] += xk * wr[1];
            acc[2] += xk * wr[2]; acc[3] += xk * wr[3];
            acc[4] += xk * wr[4]; acc[5] += xk * wr[5];
        }
    }
    __syncthreads();
    // repack via LDS out[GTN][48] (reuses xls region)
    float* out = xls;
    *(float2*)(out + n * 48 + q * 6)     = make_float2(acc[0], acc[1]);
    *(float2*)(out + n * 48 + q * 6 + 2) = make_float2(acc[2], acc[3]);
    *(float2*)(out + n * 48 + q * 6 + 4) = make_float2(acc[4], acc[5]);
    __syncthreads();
    for (int f = tid; f < GTN * 32; f += 256) {
        int nn = f >> 5, c = f & 31;
        int gnn = node0 + nn;
        if (gnn >= N) continue;
        if (c < 16) {
            unsigned int lo = f2bf(out[nn * 48 + c]);
            unsigned int hi = f2bf(out[nn * 48 + 16 + c]);
            h01i[(size_t)gnn * 16 + c] = lo | (hi << 16);
        } else {
            xr[(size_t)gnn * 16 + (c - 16)] = out[nn * 48 + 32 + (c - 16)];
        }
    }
}

__device__ __forceinline__ void bin_part(
    int* __restrict__ smem, int bb, int tid,
    const int* __restrict__ ei, const float* __restrict__ ea,
    int* __restrict__ gcur, int2* __restrict__ staging, int E, int nbuk)
{
    int* bcnt  = smem;                  // NBUK_MAX
    int* gbase = bcnt + NBUK_MAX;       // NBUK_MAX
    for (int i = tid; i < nbuk; i += 256) bcnt[i] = 0;
    __syncthreads();

    int base = bb * CHUNK;
    int lrank[16];
#pragma unroll
    for (int i = 0; i < 16; ++i) {
        int e = base + i * 256 + tid;
        lrank[i] = 0;
        if (e < E) lrank[i] = atomicAdd(&bcnt[ei[E + e] >> SHIFT], 1);
    }
    __syncthreads();
    for (int b = tid; b < nbuk; b += 256) {
        int c = bcnt[b];
        gbase[b] = c ? atomicAdd(&gcur[b], c) : 0;
    }
    __syncthreads();
#pragma unroll
    for (int i = 0; i < 16; ++i) {
        int e = base + i * 256 + tid;
        if (e < E) {
            int s = ei[e];
            int d = ei[E + e];
            int b = d >> SHIFT;
            int p = gbase[b] + lrank[i];
            if (p < CAP)
                staging[(size_t)b * CAP + p] =
                    make_int2(s | ((d & (BNODES - 1)) << 17), __float_as_int(ea[e]));
        }
    }
}

// even blockIdx -> gemm block, odd -> bin block
__global__ __launch_bounds__(256, 3) void phase1_kernel(
    const float* __restrict__ x, const float* __restrict__ W1,
    const float* __restrict__ root1, unsigned int* __restrict__ h01i,
    float* __restrict__ xr,
    const int* __restrict__ ei, const float* __restrict__ ea,
    int* __restrict__ gcur, int2* __restrict__ staging,
    int N, int E, int nbuk, int gemmBlocks, int binBlocks)
{
    __shared__ float smem[GTN * XPITCH + 128 * 48];   // 41.5KB union
    int tid = threadIdx.x;
    int bid = blockIdx.x;
    int sub = bid >> 1;
    if ((bid & 1) == 0) {
        if (sub < gemmBlocks)
            gemm_part(smem, sub, tid, x, W1, root1, h01i, xr, N);
    } else {
        if (sub < binBlocks)
            bin_part((int*)smem, sub, tid, ei, ea, gcur, staging, E, nbuk);
    }
}

// In-place per-bucket counting sort; emits PACKED u32 records {src|wq<<17}
// into the bucket's own byte region (no cross-block overlap).
__global__ __launch_bounds__(256) void csr_build_kernel(
    int2* __restrict__ staging, const int* __restrict__ gcur,
    int* __restrict__ roff, int* __restrict__ cnt, int N)
{
    __shared__ int2 rin[CAP];
    __shared__ unsigned int rout[CAP];
    __shared__ int hist[BNODES];
    __shared__ int sscan[BNODES];
    __shared__ int wcur[BNODES];
    int tid = threadIdx.x;
    int b = blockIdx.x;
    int m = gcur[b];
    if (m > CAP) m = CAP;
    int2* sp = staging + (size_t)b * CAP;

    if (tid < BNODES) { hist[tid] = 0; wcur[tid] = 0; }
    __syncthreads();
    for (int k = tid; k < m; k += 256) {
        int2 r = sp[k];
        rin[k] = r;
        atomicAdd(&hist[r.x >> 17], 1);
    }
    __syncthreads();
    if (tid < BNODES) sscan[tid] = hist[tid];
    __syncthreads();
    for (int off = 1; off < BNODES; off <<= 1) {
        int t = (tid < BNODES && tid >= off) ? sscan[tid - off] : 0;
        __syncthreads();
        if (tid < BNODES) sscan[tid] += t;
        __syncthreads();
    }
    for (int k = tid; k < m; k += 256) {
        int2 r = rin[k];
        int dl = r.x >> 17;
        int pos = (sscan[dl] - hist[dl]) + atomicAdd(&wcur[dl], 1);
        float w = __int_as_float(r.y);
        int wq = (int)(w * 32768.0f + 0.5f);
        if (wq > 32767) wq = 32767;
        rout[pos] = (unsigned int)(r.x & 0x1FFFF) | ((unsigned int)wq << 17);
    }
    __syncthreads();
    unsigned int* sp32 = (unsigned int*)sp;     // same byte region as bucket b
    for (int k = tid; k < m; k += 256) sp32[k] = rout[k];
    if (tid < BNODES) {
        int n = b * BNODES + tid;
        if (n < N) {
            roff[n] = b * (CAP * 2) + (sscan[tid] - hist[tid]);  // u32 index
            cnt[n]  = hist[tid];
        }
    }
}

// Fused layer-1 gather + finalize: 16 lanes/node, lane c owns channel c.
__global__ __launch_bounds__(256) void gather1f_kernel(
    const unsigned int* __restrict__ staging, const int* __restrict__ roff,
    const int* __restrict__ cnt, const unsigned int* __restrict__ h01i,
    const float* __restrict__ xr, const float* __restrict__ b1,
    const float* __restrict__ root2, const float* __restrict__ b2,
    unsigned short* __restrict__ hb, float* __restrict__ hrb, int N)
{
    __shared__ float r2s[160];
    __shared__ float b1s[16];
    __shared__ float b2s[10];
    int tid = threadIdx.x;
    if (tid < 160) r2s[tid] = root2[tid];
    if (tid < 16)  b1s[tid] = b1[tid];
    if (tid < 10)  b2s[tid] = b2[tid];
    __syncthreads();
    int t = blockIdx.x * 256 + tid;
    int n = t >> 4;
    int c = t & 15;
    if (n >= N) return;
    int start = roff[n];
    int m = cnt[n];
    float acc = 0.f;
#pragma unroll 4
    for (int k = 0; k < m; ++k) {
        unsigned int rec = staging[(size_t)start + k];
        float w = (float)(rec >> 17) * (1.0f / 32768.0f);
        unsigned int v = h01i[(size_t)(rec & 0x1FFFF) * 16 + c];
        float a  = __uint_as_float(v << 16);            // h0 (lo bf16)
        float bb = __uint_as_float(v & 0xFFFF0000u);    // h1 (hi bf16)
        acc += a + w * (bb - a);
    }
    float invd = 1.0f / fmaxf((float)m, 1.0f);
    float hv = acc * invd + xr[(size_t)n * 16 + c] + b1s[c];
    hv = hv > 0.f ? hv : expm1f(hv);
    hb[(size_t)n * 16 + c] = f2bf(hv);

    float r[10];
#pragma unroll
    for (int j = 0; j < 10; ++j) r[j] = hv * r2s[c * 10 + j];
#pragma unroll
    for (int off = 1; off < 16; off <<= 1) {
#pragma unroll
        for (int j = 0; j < 10; ++j) r[j] += __shfl_xor(r[j], off);
    }
    if (c == 0) {
        float* hp = hrb + (size_t)n * 10;
#pragma unroll
        for (int j = 0; j < 10; ++j) hp[j] = r[j] + b2s[j];
    }
}

// Fused layer-2 gather + finalize.
__global__ __launch_bounds__(256) void gather2f_kernel(
    const unsigned int* __restrict__ staging, const int* __restrict__ roff,
    const int* __restrict__ cnt, const unsigned short* __restrict__ hb,
    const float* __restrict__ hrb, const float* __restrict__ W2,
    float* __restrict__ out, int N)
{
    __shared__ float w2s[320];
    int tid = threadIdx.x;
    for (int idx = tid; idx < 320; idx += 256) w2s[idx] = W2[idx];
    __syncthreads();
    int t = blockIdx.x * 256 + tid;
    int n = t >> 4;
    int c = t & 15;
    if (n >= N) return;
    int start = roff[n];
    int m = cnt[n];
    float p = 0.f, q = 0.f;
#pragma unroll 4
    for (int k = 0; k < m; ++k) {
        unsigned int rec = staging[(size_t)start + k];
        float w = (float)(rec >> 17) * (1.0f / 32768.0f);
        float v = __uint_as_float(((unsigned int)hb[(size_t)(rec & 0x1FFFF) * 16 + c]) << 16);
        p += (1.f - w) * v;
        q += w * v;
    }
    float invd = 1.0f / fmaxf((float)m, 1.0f);
    float o[10];
#pragma unroll
    for (int j = 0; j < 10; ++j)
        o[j] = p * w2s[c * 10 + j] + q * w2s[160 + c * 10 + j];
#pragma unroll
    for (int off = 1; off < 16; off <<= 1) {
#pragma unroll
        for (int j = 0; j < 10; ++j) o[j] += __shfl_xor(o[j], off);
    }
    if (c == 0) {
        float* op = out + (size_t)n * 10;
        const float* hp = hrb + (size_t)n * 10;
#pragma unroll
        for (int j = 0; j < 10; ++j) op[j] = o[j] * invd + hp[j];
    }
}

extern "C" void kernel_launch(void* const* d_in, const int* in_sizes, int n_in,
                              void* d_out, int out_size, void* d_ws, size_t ws_size,
                              hipStream_t stream)
{
    const float* x     = (const float*)d_in[0];
    const int*   ei    = (const int*)d_in[1];   // (2,E)
    const float* ea    = (const float*)d_in[2]; // (E,1)
    const float* W1    = (const float*)d_in[3]; // (2,128,16)
    const float* root1 = (const float*)d_in[4]; // (128,16)
    const float* b1    = (const float*)d_in[5]; // (16,)
    const float* W2    = (const float*)d_in[6]; // (2,16,10)
    const float* root2 = (const float*)d_in[7]; // (16,10)
    const float* b2    = (const float*)d_in[8]; // (10,)
    float* out = (float*)d_out;

    int N = in_sizes[0] / 128;
    int E = in_sizes[2];
    int nbuk = (N + BNODES - 1) / BNODES;   // 782

    // workspace ~36 MB (same layout family as passing r10/r13):
    //   staging 15.2MB | h01i N*16 u32 | xr N*16 f | hrb N*10 f
    //   hb N*16 bf16 | cnt N | roff N | gcur nbuk
    char* ws = (char*)d_ws;
    int2*  staging = (int2*)ws;
    unsigned int* h01i = (unsigned int*)(ws + (size_t)nbuk * CAP * 8);
    float* xr    = (float*)(h01i + (size_t)N * 16);
    float* hrb   = xr + (size_t)N * 16;
    unsigned short* hb = (unsigned short*)(hrb + (size_t)N * 10);
    int*   cnt   = (int*)(hb + (size_t)N * 16);
    int*   roff  = cnt + N;
    int*   gcur  = roff + N;

    int nb_e16 = (N * 16 + 255) / 256;
    int gemmBlocks = (N + GTN - 1) / GTN;              // 3125
    int binBlocks  = (E + CHUNK - 1) / CHUNK;          // 391
    int mixBlocks  = 2 * ((gemmBlocks > binBlocks) ? gemmBlocks : binBlocks);

    hipMemsetAsync(gcur, 0, (size_t)nbuk * sizeof(int), stream);

    phase1_kernel   <<<mixBlocks, 256, 0, stream>>>(
        x, W1, root1, h01i, xr, ei, ea, gcur, staging, N, E, nbuk,
        gemmBlocks, binBlocks);
    csr_build_kernel<<<nbuk, 256, 0, stream>>>(staging, gcur, roff, cnt, N);
    gather1f_kernel <<<nb_e16, 256, 0, stream>>>((const unsigned int*)staging,
                                                 roff, cnt, h01i, xr,
                                                 b1, root2, b2, hb, hrb, N);
    gather2f_kernel <<<nb_e16, 256, 0, stream>>>((const unsigned int*)staging,
                                                 roff, cnt, hb, hrb,
                                                 W2, out, N);
}

// Round 15
// 134.778 us; speedup vs baseline: 1.2887x; 1.2887x over previous
//
#include <hip/hip_runtime.h>
#include <math.h>

// ---------------------------------------------------------------------------
// spline_net r15: revert gemm to r13's proven form (128 nodes/block, permuted
// LDS weights — r14's 32-node tile re-staged the 24.6KB weight tile 4x as
// often and dropped occupancy: phase1 69->115us). KEEP r14's downstream wins
// (packed 4B records, unroll-4 gathers: ~-20us). One knob: gemm k-unroll 8.
// N=100000, F_IN=128, HID=16, C=10, E=1600000
// ---------------------------------------------------------------------------

#define SHIFT    7            // 128 nodes per bucket
#define BNODES   128
#define NBUK_MAX 800          // supports N <= 102400
#define CAP      2432         // bucket capacity; mean 2046, sigma ~45 -> +8.5σ
#define CHUNK    4096         // edges per bin block

__device__ __forceinline__ unsigned short f2bf(float f) {
    unsigned int u = __float_as_uint(f);
    u += 0x7FFF + ((u >> 16) & 1);        // round to nearest even
    return (unsigned short)(u >> 16);
}

// ---- fused phase 1: gemm part (LDS weights, permuted cols) + bin part ------
// LDS col order per k: [0:8)=W1[0][:,0:8) [8:16)=W1[1][:,0:8) [16:24)=root1[:,0:8)
//   [24:32)=W1[0][:,8:16) [32:40)=W1[1][:,8:16) [40:48)=root1[:,8:16)

__device__ __forceinline__ void gemm_part(
    float* __restrict__ Ws, int gb, int tid,
    const float* __restrict__ x, const float* __restrict__ W1,
    const float* __restrict__ root1, unsigned int* __restrict__ h01i,
    float* __restrict__ xr, int N)
{
    for (int idx = tid; idx < 128 * 48; idx += 256) {
        int k = idx / 48, j = idx % 48;
        int grp = j >> 3, t = j & 7;
        float v;
        switch (grp) {
            case 0: v = W1[k * 16 + t];            break;
            case 1: v = W1[2048 + k * 16 + t];     break;
            case 2: v = root1[k * 16 + t];         break;
            case 3: v = W1[k * 16 + 8 + t];        break;
            case 4: v = W1[2048 + k * 16 + 8 + t]; break;
            default: v = root1[k * 16 + 8 + t];    break;
        }
        Ws[idx] = v;
    }
    __syncthreads();
    int nl   = tid >> 1;          // node within block
    int half = tid & 1;           // channel group 0-7 / 8-15
    int n = gb * 128 + nl;
    if (n >= N) return;

    float acc[24];
#pragma unroll
    for (int j = 0; j < 24; ++j) acc[j] = 0.f;

    const float4* xrow = (const float4*)(x + (size_t)n * 128);
    const float4* wbase = (const float4*)(Ws + half * 24);
#pragma unroll 8
    for (int k4 = 0; k4 < 32; ++k4) {
        float4 xv = xrow[k4];
        float xs[4] = {xv.x, xv.y, xv.z, xv.w};
#pragma unroll
        for (int kk = 0; kk < 4; ++kk) {
            float xk = xs[kk];
            const float4* w4 = wbase + ((k4 * 4 + kk) * 48) / 4;
#pragma unroll
            for (int q = 0; q < 6; ++q) {
                float4 wv = w4[q];
                acc[q * 4 + 0] += xk * wv.x;
                acc[q * 4 + 1] += xk * wv.y;
                acc[q * 4 + 2] += xk * wv.z;
                acc[q * 4 + 3] += xk * wv.w;
            }
        }
    }
    // acc[0..7]=h0[ch], acc[8..15]=h1[ch], acc[16..23]=xr[ch], ch=half*8+t
    int cb = half * 8;
#pragma unroll
    for (int t = 0; t < 8; ++t)
        h01i[(size_t)n * 16 + cb + t] =
            (unsigned int)f2bf(acc[t]) | ((unsigned int)f2bf(acc[8 + t]) << 16);
#pragma unroll
    for (int t = 0; t < 8; ++t)
        xr[(size_t)n * 16 + cb + t] = acc[16 + t];
}

__device__ __forceinline__ void bin_part(
    int* __restrict__ smem, int bb, int tid,
    const int* __restrict__ ei, const float* __restrict__ ea,
    int* __restrict__ gcur, int2* __restrict__ staging, int E, int nbuk)
{
    int* bcnt  = smem;                  // NBUK_MAX
    int* gbase = bcnt + NBUK_MAX;       // NBUK_MAX
    for (int i = tid; i < nbuk; i += 256) bcnt[i] = 0;
    __syncthreads();

    int base = bb * CHUNK;
    int lrank[16];
#pragma unroll
    for (int i = 0; i < 16; ++i) {
        int e = base + i * 256 + tid;
        lrank[i] = 0;
        if (e < E) lrank[i] = atomicAdd(&bcnt[ei[E + e] >> SHIFT], 1);
    }
    __syncthreads();
    for (int b = tid; b < nbuk; b += 256) {
        int c = bcnt[b];
        gbase[b] = c ? atomicAdd(&gcur[b], c) : 0;
    }
    __syncthreads();
#pragma unroll
    for (int i = 0; i < 16; ++i) {
        int e = base + i * 256 + tid;
        if (e < E) {
            int s = ei[e];
            int d = ei[E + e];
            int b = d >> SHIFT;
            int p = gbase[b] + lrank[i];
            if (p < CAP)
                staging[(size_t)b * CAP + p] =
                    make_int2(s | ((d & (BNODES - 1)) << 17), __float_as_int(ea[e]));
        }
    }
}

// even blockIdx -> gemm block, odd -> bin block
__global__ __launch_bounds__(256, 4) void phase1_kernel(
    const float* __restrict__ x, const float* __restrict__ W1,
    const float* __restrict__ root1, unsigned int* __restrict__ h01i,
    float* __restrict__ xr,
    const int* __restrict__ ei, const float* __restrict__ ea,
    int* __restrict__ gcur, int2* __restrict__ staging,
    int N, int E, int nbuk, int gemmBlocks, int binBlocks)
{
    __shared__ float smem[128 * 48];   // gemm Ws (24.6KB) | bin counters (6.4KB)
    int tid = threadIdx.x;
    int bid = blockIdx.x;
    int sub = bid >> 1;
    if ((bid & 1) == 0) {
        if (sub < gemmBlocks)
            gemm_part(smem, sub, tid, x, W1, root1, h01i, xr, N);
    } else {
        if (sub < binBlocks)
            bin_part((int*)smem, sub, tid, ei, ea, gcur, staging, E, nbuk);
    }
}

// In-place per-bucket counting sort; emits PACKED u32 records {src|wq<<17}
// into the bucket's own byte region (no cross-block overlap).
__global__ __launch_bounds__(256) void csr_build_kernel(
    int2* __restrict__ staging, const int* __restrict__ gcur,
    int* __restrict__ roff, int* __restrict__ cnt, int N)
{
    __shared__ int2 rin[CAP];
    __shared__ unsigned int rout[CAP];
    __shared__ int hist[BNODES];
    __shared__ int sscan[BNODES];
    __shared__ int wcur[BNODES];
    int tid = threadIdx.x;
    int b = blockIdx.x;
    int m = gcur[b];
    if (m > CAP) m = CAP;
    int2* sp = staging + (size_t)b * CAP;

    if (tid < BNODES) { hist[tid] = 0; wcur[tid] = 0; }
    __syncthreads();
    for (int k = tid; k < m; k += 256) {
        int2 r = sp[k];
        rin[k] = r;
        atomicAdd(&hist[r.x >> 17], 1);
    }
    __syncthreads();
    if (tid < BNODES) sscan[tid] = hist[tid];
    __syncthreads();
    for (int off = 1; off < BNODES; off <<= 1) {
        int t = (tid < BNODES && tid >= off) ? sscan[tid - off] : 0;
        __syncthreads();
        if (tid < BNODES) sscan[tid] += t;
        __syncthreads();
    }
    for (int k = tid; k < m; k += 256) {
        int2 r = rin[k];
        int dl = r.x >> 17;
        int pos = (sscan[dl] - hist[dl]) + atomicAdd(&wcur[dl], 1);
        float w = __int_as_float(r.y);
        int wq = (int)(w * 32768.0f + 0.5f);
        if (wq > 32767) wq = 32767;
        rout[pos] = (unsigned int)(r.x & 0x1FFFF) | ((unsigned int)wq << 17);
    }
    __syncthreads();
    unsigned int* sp32 = (unsigned int*)sp;     // same byte region as bucket b
    for (int k = tid; k < m; k += 256) sp32[k] = rout[k];
    if (tid < BNODES) {
        int n = b * BNODES + tid;
        if (n < N) {
            roff[n] = b * (CAP * 2) + (sscan[tid] - hist[tid]);  // u32 index
            cnt[n]  = hist[tid];
        }
    }
}

// Fused layer-1 gather + finalize: 16 lanes/node, lane c owns channel c.
__global__ __launch_bounds__(256) void gather1f_kernel(
    const unsigned int* __restrict__ staging, const int* __restrict__ roff,
    const int* __restrict__ cnt, const unsigned int* __restrict__ h01i,
    const float* __restrict__ xr, const float* __restrict__ b1,
    const float* __restrict__ root2, const float* __restrict__ b2,
    unsigned short* __restrict__ hb, float* __restrict__ hrb, int N)
{
    __shared__ float r2s[160];
    __shared__ float b1s[16];
    __shared__ float b2s[10];
    int tid = threadIdx.x;
    if (tid < 160) r2s[tid] = root2[tid];
    if (tid < 16)  b1s[tid] = b1[tid];
    if (tid < 10)  b2s[tid] = b2[tid];
    __syncthreads();
    int t = blockIdx.x * 256 + tid;
    int n = t >> 4;
    int c = t & 15;
    if (n >= N) return;
    int start = roff[n];
    int m = cnt[n];
    float acc = 0.f;
#pragma unroll 4
    for (int k = 0; k < m; ++k) {
        unsigned int rec = staging[(size_t)start + k];
        float w = (float)(rec >> 17) * (1.0f / 32768.0f);
        unsigned int v = h01i[(size_t)(rec & 0x1FFFF) * 16 + c];
        float a  = __uint_as_float(v << 16);            // h0 (lo bf16)
        float bb = __uint_as_float(v & 0xFFFF0000u);    // h1 (hi bf16)
        acc += a + w * (bb - a);
    }
    float invd = 1.0f / fmaxf((float)m, 1.0f);
    float hv = acc * invd + xr[(size_t)n * 16 + c] + b1s[c];
    hv = hv > 0.f ? hv : expm1f(hv);
    hb[(size_t)n * 16 + c] = f2bf(hv);

    float r[10];
#pragma unroll
    for (int j = 0; j < 10; ++j) r[j] = hv * r2s[c * 10 + j];
#pragma unroll
    for (int off = 1; off < 16; off <<= 1) {
#pragma unroll
        for (int j = 0; j < 10; ++j) r[j] += __shfl_xor(r[j], off);
    }
    if (c == 0) {
        float* hp = hrb + (size_t)n * 10;
#pragma unroll
        for (int j = 0; j < 10; ++j) hp[j] = r[j] + b2s[j];
    }
}

// Fused layer-2 gather + finalize.
__global__ __launch_bounds__(256) void gather2f_kernel(
    const unsigned int* __restrict__ staging, const int* __restrict__ roff,
    const int* __restrict__ cnt, const unsigned short* __restrict__ hb,
    const float* __restrict__ hrb, const float* __restrict__ W2,
    float* __restrict__ out, int N)
{
    __shared__ float w2s[320];
    int tid = threadIdx.x;
    for (int idx = tid; idx < 320; idx += 256) w2s[idx] = W2[idx];
    __syncthreads();
    int t = blockIdx.x * 256 + tid;
    int n = t >> 4;
    int c = t & 15;
    if (n >= N) return;
    int start = roff[n];
    int m = cnt[n];
    float p = 0.f, q = 0.f;
#pragma unroll 4
    for (int k = 0; k < m; ++k) {
        unsigned int rec = staging[(size_t)start + k];
        float w = (float)(rec >> 17) * (1.0f / 32768.0f);
        float v = __uint_as_float(((unsigned int)hb[(size_t)(rec & 0x1FFFF) * 16 + c]) << 16);
        p += (1.f - w) * v;
        q += w * v;
    }
    float invd = 1.0f / fmaxf((float)m, 1.0f);
    float o[10];
#pragma unroll
    for (int j = 0; j < 10; ++j)
        o[j] = p * w2s[c * 10 + j] + q * w2s[160 + c * 10 + j];
#pragma unroll
    for (int off = 1; off < 16; off <<= 1) {
#pragma unroll
        for (int j = 0; j < 10; ++j) o[j] += __shfl_xor(o[j], off);
    }
    if (c == 0) {
        float* op = out + (size_t)n * 10;
        const float* hp = hrb + (size_t)n * 10;
#pragma unroll
        for (int j = 0; j < 10; ++j) op[j] = o[j] * invd + hp[j];
    }
}

extern "C" void kernel_launch(void* const* d_in, const int* in_sizes, int n_in,
                              void* d_out, int out_size, void* d_ws, size_t ws_size,
                              hipStream_t stream)
{
    const float* x     = (const float*)d_in[0];
    const int*   ei    = (const int*)d_in[1];   // (2,E)
    const float* ea    = (const float*)d_in[2]; // (E,1)
    const float* W1    = (const float*)d_in[3]; // (2,128,16)
    const float* root1 = (const float*)d_in[4]; // (128,16)
    const float* b1    = (const float*)d_in[5]; // (16,)
    const float* W2    = (const float*)d_in[6]; // (2,16,10)
    const float* root2 = (const float*)d_in[7]; // (16,10)
    const float* b2    = (const float*)d_in[8]; // (10,)
    float* out = (float*)d_out;

    int N = in_sizes[0] / 128;
    int E = in_sizes[2];
    int nbuk = (N + BNODES - 1) / BNODES;   // 782

    // workspace ~36 MB (same layout as passing r13/r14):
    //   staging 15.2MB | h01i N*16 u32 | xr N*16 f | hrb N*10 f
    //   hb N*16 bf16 | cnt N | roff N | gcur nbuk
    char* ws = (char*)d_ws;
    int2*  staging = (int2*)ws;
    unsigned int* h01i = (unsigned int*)(ws + (size_t)nbuk * CAP * 8);
    float* xr    = (float*)(h01i + (size_t)N * 16);
    float* hrb   = xr + (size_t)N * 16;
    unsigned short* hb = (unsigned short*)(hrb + (size_t)N * 10);
    int*   cnt   = (int*)(hb + (size_t)N * 16);
    int*   roff  = cnt + N;
    int*   gcur  = roff + N;

    int nb_e16 = (N * 16 + 255) / 256;
    int gemmBlocks = (N + 127) / 128;                  // 782
    int binBlocks  = (E + CHUNK - 1) / CHUNK;          // 391
    int mixBlocks  = 2 * ((gemmBlocks > binBlocks) ? gemmBlocks : binBlocks);

    hipMemsetAsync(gcur, 0, (size_t)nbuk * sizeof(int), stream);

    phase1_kernel   <<<mixBlocks, 256, 0, stream>>>(
        x, W1, root1, h01i, xr, ei, ea, gcur, staging, N, E, nbuk,
        gemmBlocks, binBlocks);
    csr_build_kernel<<<nbuk, 256, 0, stream>>>(staging, gcur, roff, cnt, N);
    gather1f_kernel <<<nb_e16, 256, 0, stream>>>((const unsigned int*)staging,
                                                 roff, cnt, h01i, xr,
                                                 b1, root2, b2, hb, hrb, N);
    gather2f_kernel <<<nb_e16, 256, 0, stream>>>((const unsigned int*)staging,
                                                 roff, cnt, hb, hrb,
                                                 W2, out, N);
}